// Round 4
// baseline (11419.309 us; speedup 1.0000x reference)
//
#include <hip/hip_runtime.h>
#include <math.h>

// LSTM H=1024, T=2048, IN=5, OUT=9, batch=1 on MI355X.
// 64 persistent WGs x 512 threads (always co-resident: 64 << capacity).
// Weights f32 in registers: wave w of WG b owns rows {gate g, j in
// {j0, j0+1}} with j0 = b*16 + 2w; lane owns row (lane&7), cols
// [(lane>>3)*128, +128) -> 128 f32 regs. Cross-WG h transport: tagged
// (u32 tag | 2x bf16) atoms, 512 per step, depth-4 ring in d_ws, laid out
// so consumer lane L polls one 64B line (atoms of WG L). Wave0 polls,
// unpacks to LDS f32, raises LDS flag; waves 1-7 spin on the flag.
// No __syncthreads in the time loop.

typedef unsigned int u32;
typedef unsigned long long u64;

constexpr int kH     = 1024;
constexpr int kT     = 2048;
constexpr int kIN    = 5;
constexpr int kOUT   = 9;
constexpr int kNWG   = 64;
constexpr int kBLOCK = 512;
constexpr int kAtoms = 512;          // 64 WG x 8 waves, one atom each
constexpr int kCols  = 128;          // h-columns per lane

__device__ __forceinline__ float sigm_(float v) {
  return 1.0f / (1.0f + expf(-v));
}
__device__ __forceinline__ float tanh_(float v) {
  return 1.0f - 2.0f / (expf(2.0f * v) + 1.0f);
}
__device__ __forceinline__ u32 bf16_rne(float f) {
  u32 b = __float_as_uint(f);
  return (b + 0x7FFFu + ((b >> 16) & 1u)) >> 16;
}
__device__ __forceinline__ float lo_f(u32 p) { return __uint_as_float(p << 16); }
__device__ __forceinline__ float hi_f(u32 p) { return __uint_as_float(p & 0xFFFF0000u); }

__global__ __launch_bounds__(kBLOCK, 2) void lstm_line(
    const float* __restrict__ x,     // [T,1,IN]
    const float* __restrict__ w_ih,  // [4H,IN]
    const float* __restrict__ w_hh,  // [4H,H]
    const float* __restrict__ b_ih,  // [4H]
    const float* __restrict__ b_hh,  // [4H]
    const float* __restrict__ w_out, // [OUT,H]
    const float* __restrict__ b_out, // [OUT]
    float* __restrict__ out,         // [OUT]
    u64* __restrict__ ring) {        // ring[4][kAtoms]
  const int pid  = blockIdx.x;
  const int tid  = threadIdx.x;
  const int w    = tid >> 6;
  const int lane = tid & 63;

  __shared__ float x_lds[kT * kIN];  // 40 KiB
  __shared__ float h_lds[kH];        // 4 KiB (f32, unpacked)
  __shared__ int   hflag;

  for (int i = tid; i < kT * kIN; i += kBLOCK) x_lds[i] = x[i];
  if (tid == 0) hflag = 0;

  // Row/col ownership.
  const int j0      = pid * 16 + 2 * w;
  const int rmy     = lane & 7;                   // row index within wave
  const int grow    = (rmy & 3) * kH + j0 + (rmy >> 2);
  const int colbase = (lane >> 3) * kCols;

  // 128 f32 recurrent weights in registers (compile-time indexed).
  float wreg[kCols];
  {
    const float* sp = w_hh + (size_t)grow * kH + colbase;
#pragma unroll
    for (int m = 0; m < kCols; ++m) wreg[m] = sp[m];
  }
  float wihr[kIN];
#pragma unroll
  for (int k = 0; k < kIN; ++k) wihr[k] = w_ih[grow * kIN + k];
  const float biasr = b_ih[grow] + b_hh[grow];

  float cst = 0.0f;  // cell state for this lane's j (duplicated per quad)
  __syncthreads();   // x_lds + hflag ready — only barrier in the kernel

  for (int t = 0; t < kT; ++t) {
    // gx for this lane's row — VALU work before the wait
    float gx = biasr;
#pragma unroll
    for (int k = 0; k < kIN; ++k) gx = fmaf(wihr[k], x_lds[t * kIN + k], gx);

    // ---- acquire h_t ----
    if (w == 0) {
      // lane L polls the 8 atoms of WG L: one contiguous 64B line.
      const u64* pb = ring + (size_t)(t & 3) * kAtoms + lane * 8;
      u64 a[8];
      bool ok;
      do {
#pragma unroll
        for (int k = 0; k < 8; ++k)
          a[k] = __hip_atomic_load(pb + k, __ATOMIC_RELAXED,
                                   __HIP_MEMORY_SCOPE_AGENT);
        ok = true;
#pragma unroll
        for (int k = 0; k < 8; ++k) ok = ok && ((u32)(a[k] >> 32) == (u32)t);
      } while (!__all(ok));
      // unpack: atom (L,k) carries h[L*16 + 2k], h[L*16 + 2k + 1]
#pragma unroll
      for (int k = 0; k < 8; ++k) {
        const u32 d = (u32)a[k];
        h_lds[lane * 16 + 2 * k]     = lo_f(d);
        h_lds[lane * 16 + 2 * k + 1] = hi_f(d);
      }
      if (lane == 0)
        __hip_atomic_store(&hflag, t + 1, __ATOMIC_RELEASE,
                           __HIP_MEMORY_SCOPE_WORKGROUP);
    } else {
      while (__hip_atomic_load(&hflag, __ATOMIC_ACQUIRE,
                               __HIP_MEMORY_SCOPE_WORKGROUP) < t + 1) { }
    }
    // wave0: its own ds_writes complete before its ds_reads (program order).

    // ---- matvec: 1 row x 128 cols per lane, 4 acc chains ----
    float acc0 = 0.0f, acc1 = 0.0f, acc2 = 0.0f, acc3 = 0.0f;
#pragma unroll
    for (int m = 0; m < kCols; m += 4) {
      acc0 = fmaf(wreg[m + 0], h_lds[colbase + m + 0], acc0);
      acc1 = fmaf(wreg[m + 1], h_lds[colbase + m + 1], acc1);
      acc2 = fmaf(wreg[m + 2], h_lds[colbase + m + 2], acc2);
      acc3 = fmaf(wreg[m + 3], h_lds[colbase + m + 3], acc3);
    }
    float f = (acc0 + acc1) + (acc2 + acc3);
    // reduce across the 8 lanes sharing this row (xor 8,16,32)
    f += __shfl_xor(f, 8);
    f += __shfl_xor(f, 16);
    f += __shfl_xor(f, 32);

    // ---- nonlinearity: every lane has its row total; gate = lane&3 ----
    const float gtot = f + gx;
    const int   gate = lane & 3;
    const float u    = (gate == 2) ? 2.0f * gtot : gtot;
    float n = sigm_(u);
    n = (gate == 2) ? (2.0f * n - 1.0f) : n;

    // ---- quad gather + state update (quads {0-3}: j0, {4-7}: j0+1) ----
    const int   qb = lane & ~3;
    const float ni = __shfl(n, qb + 0);
    const float nf = __shfl(n, qb + 1);
    const float ng = __shfl(n, qb + 2);
    const float no = __shfl(n, qb + 3);
    cst = nf * cst + ni * ng;
    const float hval = no * tanh_(cst);

    // ---- publish: lane0 packs (h_j0, h_j0+1) + tag, one 8B store ----
    const float h1 = __shfl(hval, 4);
    if (lane == 0) {
      const u64 pack = ((u64)(u32)(t + 1) << 32) |
                       (u64)(bf16_rne(hval) | (bf16_rne(h1) << 16));
      __hip_atomic_store(ring + (size_t)((t + 1) & 3) * kAtoms + pid * 8 + w,
                         pack, __ATOMIC_RELAXED, __HIP_MEMORY_SCOPE_AGENT);
    }
  }

  // ---- epilogue: tanh -> 9x1024 matvec -> log_softmax (pid0 wave0) ----
  if (pid == 0 && w == 0) {
    const u64* pb = ring + (size_t)(kT & 3) * kAtoms + lane * 8;
    u64 a[8];
    bool ok;
    do {
#pragma unroll
      for (int k = 0; k < 8; ++k)
        a[k] = __hip_atomic_load(pb + k, __ATOMIC_RELAXED,
                                 __HIP_MEMORY_SCOPE_AGENT);
      ok = true;
#pragma unroll
      for (int k = 0; k < 8; ++k) ok = ok && ((u32)(a[k] >> 32) == (u32)kT);
    } while (!__all(ok));

    // lane L holds h[16L .. 16L+15] -> z = tanh(h)
    float z[16];
#pragma unroll
    for (int k = 0; k < 8; ++k) {
      const u32 d = (u32)a[k];
      z[2 * k]     = tanh_(lo_f(d));
      z[2 * k + 1] = tanh_(hi_f(d));
    }
    float logits[kOUT];
#pragma unroll
    for (int r = 0; r < kOUT; ++r) {
      const float* wr = w_out + (size_t)r * kH + lane * 16;
      float acc = 0.0f;
#pragma unroll
      for (int i = 0; i < 16; ++i) acc = fmaf(wr[i], z[i], acc);
#pragma unroll
      for (int off = 32; off; off >>= 1) acc += __shfl_xor(acc, off);
      logits[r] = acc + b_out[r];
    }
    if (lane == 0) {
      float m = logits[0];
#pragma unroll
      for (int r = 1; r < kOUT; ++r) m = fmaxf(m, logits[r]);
      float s = 0.0f;
#pragma unroll
      for (int r = 0; r < kOUT; ++r) s += expf(logits[r] - m);
      const float lse = m + logf(s);
#pragma unroll
      for (int r = 0; r < kOUT; ++r) out[r] = logits[r] - lse;
    }
  }
}

extern "C" void kernel_launch(void* const* d_in, const int* in_sizes, int n_in,
                              void* d_out, int out_size, void* d_ws, size_t ws_size,
                              hipStream_t stream) {
  const float* x     = (const float*)d_in[0];
  const float* w_ih  = (const float*)d_in[1];
  const float* w_hh  = (const float*)d_in[2];
  const float* b_ih  = (const float*)d_in[3];
  const float* b_hh  = (const float*)d_in[4];
  const float* w_out = (const float*)d_in[5];
  const float* b_out = (const float*)d_in[6];
  float* out  = (float*)d_out;
  u64*   ring = (u64*)d_ws;

  // Zero all 4 ring slots each call: slot0 must read (tag=0, h=0) at t=0,
  // and stale tags from a prior replay must be cleared. 16 KiB.
  hipMemsetAsync(d_ws, 0, (size_t)4 * kAtoms * sizeof(u64), stream);

  lstm_line<<<kNWG, kBLOCK, 0, stream>>>(x, w_ih, w_hh, b_ih, b_hh,
                                         w_out, b_out, out, ring);
}